// Round 10
// baseline (247.309 us; speedup 1.0000x reference)
//
#include <hip/hip_runtime.h>

// Shapes: B=32, S_NEW=1, DIM=4096, H=32, KV=8, HD=128, PREV=2048, SEQ=2049
// All inputs/outputs fp32.
//
// ws layout (float offsets):
//   P1   [32][32][6144] @ 0         (6291456) qkv split-K partials
//   qkv  [32][6144]     @ 6291456   (196608)  rope'd q (scaled), k_new, v_new
//   attn [32][4096]     @ 6488064   (131072)  attention output (b, h, d)
//   P2   [32][32][4096] @ 6619136   (4194304) out-proj split-K partials
//   SC   [32][2052][32] @ 10813440  (2101248) scores [b][s][kvh], stride 65664/b
//   LINV [256][4]       @ 12914688  (1024)    1/L per (b,kv,h)
//   PA   [2048][4096]   @ 12915712  (8388608) pv block partials

#define WS_P1   0
#define WS_QKV  6291456
#define WS_ATTN 6488064
#define WS_P2   6619136
#define WS_SC   10813440
#define WS_LINV 12914688
#define WS_PA   12915712

// ---------------------------------------------------------------------------
// Skinny GEMM partial (round-3 proven): P[ks][b][n] over 128-k chunk.
// grid: (Ntot/256, 32), block: 256 threads = 128 colpairs x 2 k-groups.
// ---------------------------------------------------------------------------
__global__ __launch_bounds__(256) void gemm_skinny(
    const float* __restrict__ X,
    const float* __restrict__ W0, int e0, int ld0,
    const float* __restrict__ W1, int e1, int ld1,
    const float* __restrict__ W2, int ld2,
    float* __restrict__ P, int Ntot)
{
    __shared__ float x_t[128][36];     // transposed x chunk [kk][b], pad 36
    __shared__ float2 red[128][33];    // 2-way kg reduce, pad 33

    const int nb = blockIdx.x * 256;
    const float* W; int ld, noff;
    if (nb < e0)      { W = W0; ld = ld0; noff = 0;  }
    else if (nb < e1) { W = W1; ld = ld1; noff = e0; }
    else              { W = W2; ld = ld2; noff = e1; }

    const int k0  = blockIdx.y * 128;
    const int tid = threadIdx.x;
    const int cp  = tid & 127;
    const int kg  = tid >> 7;
    const int nn  = nb - noff + cp * 2;

    #pragma unroll
    for (int i = 0; i < 16; ++i) {
        int idx = tid + i * 256;
        int bb = idx >> 7, kk = idx & 127;
        x_t[kk][bb] = X[(size_t)bb * 4096 + k0 + kk];
    }
    __syncthreads();

    float2 acc[32];
    #pragma unroll
    for (int b = 0; b < 32; ++b) { acc[b].x = 0.f; acc[b].y = 0.f; }

    const float* Wp = W + (size_t)k0 * ld + nn;
    for (int kk0 = kg * 64; kk0 < kg * 64 + 64; kk0 += 8) {
        float2 w[8];
        #pragma unroll
        for (int u = 0; u < 8; ++u)
            w[u] = *(const float2*)&Wp[(size_t)(kk0 + u) * ld];
        #pragma unroll
        for (int u = 0; u < 8; ++u) {
            const float* xr = x_t[kk0 + u];
            #pragma unroll
            for (int bq = 0; bq < 8; ++bq) {
                float4 xv = *(const float4*)&xr[bq * 4];
                acc[bq*4+0].x += xv.x * w[u].x; acc[bq*4+0].y += xv.x * w[u].y;
                acc[bq*4+1].x += xv.y * w[u].x; acc[bq*4+1].y += xv.y * w[u].y;
                acc[bq*4+2].x += xv.z * w[u].x; acc[bq*4+2].y += xv.z * w[u].y;
                acc[bq*4+3].x += xv.w * w[u].x; acc[bq*4+3].y += xv.w * w[u].y;
            }
        }
    }

    if (kg == 1) {
        #pragma unroll
        for (int b = 0; b < 32; ++b) red[cp][b] = acc[b];
    }
    __syncthreads();
    if (kg == 0) {
        const int ks = blockIdx.y;
        #pragma unroll
        for (int b = 0; b < 32; ++b) {
            float2 o = red[cp][b];
            float2 v; v.x = acc[b].x + o.x; v.y = acc[b].y + o.y;
            *(float2*)&P[((size_t)ks * 32 + b) * Ntot + nb + cp * 2] = v;
        }
    }
}

// ---------------------------------------------------------------------------
// Reduce 32 split-K partials for QKV + fused RoPE (+ 1/sqrt(128) on q).
// ---------------------------------------------------------------------------
__global__ __launch_bounds__(128) void reduce_rope(
    const float* __restrict__ P, const float* __restrict__ freqs,
    float* __restrict__ qkv)
{
    int t = blockIdx.x * 128 + threadIdx.x;   // 0..98303
    int b = t / 3072;
    int cp = t - b * 3072;
    int n = cp * 2;
    float sx = 0.f, sy = 0.f;
    #pragma unroll
    for (int ks = 0; ks < 32; ++ks) {
        float2 v = *(const float2*)&P[((size_t)ks * 32 + b) * 6144 + n];
        sx += v.x; sy += v.y;
    }
    if (n < 5120) {
        int d = n & 127;
        float fr = freqs[d >> 1];
        float c = cosf(fr), s = sinf(fr);
        float ra = sx * c - sy * s;
        float rb = sx * s + sy * c;
        if (n < 4096) {
            const float sc = 0.08838834764831845f;  // 1/sqrt(128)
            ra *= sc; rb *= sc;
        }
        sx = ra; sy = rb;
    }
    float2 o; o.x = sx; o.y = sy;
    *(float2*)&qkv[(size_t)b * 6144 + n] = o;
}

// ---------------------------------------------------------------------------
// Scores, full-row streaming: block = (b, chunk of 32 rows), 256 threads =
// 2 teams x 2 waves; lane owns (kv=(t>>4)&7, jj=t&15 8-float d-slice).
// Team reads 16 consecutive FULL 4KB K rows (wave instr = 2KB contiguous).
// All 32 (kv,h) scores per row computed at once; 4-round shfl over 16 lanes.
// No LDS, no barriers. Chunk 63 team 1 also does the new token (s=2048).
// Writes SC[b][s][32] (contiguous 128B per row).
// ---------------------------------------------------------------------------
__global__ __launch_bounds__(256) void attn_scores(
    const float* __restrict__ qkv, const float* __restrict__ ck,
    float* __restrict__ sc)
{
    const int blk = blockIdx.x;
    const int c = blk & 63;
    const int b = blk >> 6;
    const int t = threadIdx.x;
    const int jj = t & 15;
    const int kv = (t >> 4) & 7;
    const int tm = t >> 7;

    // q[4 heads][8 floats] for this lane's (kv, d-slice), pre-scaled
    float4 q[4][2];
    {
        const float* qb = qkv + (size_t)b * 6144 + (kv * 4) * 128 + jj * 8;
        #pragma unroll
        for (int h = 0; h < 4; ++h) {
            q[h][0] = *(const float4*)(qb + h * 128);
            q[h][1] = *(const float4*)(qb + h * 128 + 4);
        }
    }

    const int r0 = c * 32 + tm * 16;
    const float* kbase = ck + ((size_t)b * 2048 + r0) * 1024 + kv * 128 + jj * 8;
    float* scb = sc + (size_t)b * 65664;

    for (int r = 0; r < 16; r += 2) {
        float4 ka[2][2];
        #pragma unroll
        for (int u = 0; u < 2; ++u) {
            ka[u][0] = *(const float4*)(kbase + (size_t)(r + u) * 1024);
            ka[u][1] = *(const float4*)(kbase + (size_t)(r + u) * 1024 + 4);
        }
        #pragma unroll
        for (int u = 0; u < 2; ++u) {
            float p[4];
            #pragma unroll
            for (int h = 0; h < 4; ++h) {
                p[h] = q[h][0].x*ka[u][0].x + q[h][0].y*ka[u][0].y
                     + q[h][0].z*ka[u][0].z + q[h][0].w*ka[u][0].w
                     + q[h][1].x*ka[u][1].x + q[h][1].y*ka[u][1].y
                     + q[h][1].z*ka[u][1].z + q[h][1].w*ka[u][1].w;
            }
            #pragma unroll
            for (int off = 1; off < 16; off <<= 1) {
                #pragma unroll
                for (int h = 0; h < 4; ++h) p[h] += __shfl_xor(p[h], off);
            }
            if (jj == 0) {
                float4 o; o.x = p[0]; o.y = p[1]; o.z = p[2]; o.w = p[3];
                *(float4*)&scb[(size_t)(r0 + r + u) * 32 + kv * 4] = o;
            }
        }
    }

    // new token (s = 2048): k_new layout [kv][128] = one 4KB row
    if (c == 63 && tm == 1) {
        const float* kr = qkv + (size_t)b * 6144 + 4096 + kv * 128 + jj * 8;
        float4 k0 = *(const float4*)kr;
        float4 k1 = *(const float4*)(kr + 4);
        float p[4];
        #pragma unroll
        for (int h = 0; h < 4; ++h) {
            p[h] = q[h][0].x*k0.x + q[h][0].y*k0.y + q[h][0].z*k0.z + q[h][0].w*k0.w
                 + q[h][1].x*k1.x + q[h][1].y*k1.y + q[h][1].z*k1.z + q[h][1].w*k1.w;
        }
        #pragma unroll
        for (int off = 1; off < 16; off <<= 1) {
            #pragma unroll
            for (int h = 0; h < 4; ++h) p[h] += __shfl_xor(p[h], off);
        }
        if (jj == 0) {
            float4 o; o.x = p[0]; o.y = p[1]; o.z = p[2]; o.w = p[3];
            *(float4*)&scb[(size_t)2048 * 32 + kv * 4] = o;
        }
    }
}

// ---------------------------------------------------------------------------
// Softmax per (b,kv), 4 heads at once. Reads SC[b][s][kv*4] (stride 128B,
// L2/L3-resident 8.4MB). Stores unnormalized exp + 1/L. grid 256 x 256.
// ---------------------------------------------------------------------------
__global__ __launch_bounds__(256) void attn_softmax(
    float* __restrict__ sc, float* __restrict__ linv)
{
    __shared__ float red[4][4];   // [wave][h]
    const int g = blockIdx.x;     // b*8+kv
    const int b = g >> 3, kv = g & 7;
    float* scb = sc + (size_t)b * 65664 + kv * 4;
    const int tid = threadIdx.x;
    const int wave = tid >> 6, lane = tid & 63;

    float4 m4; m4.x = -1e30f; m4.y = -1e30f; m4.z = -1e30f; m4.w = -1e30f;
    for (int s = tid; s < 2049; s += 256) {
        float4 v = *(const float4*)&scb[(size_t)s * 32];
        m4.x = fmaxf(m4.x, v.x); m4.y = fmaxf(m4.y, v.y);
        m4.z = fmaxf(m4.z, v.z); m4.w = fmaxf(m4.w, v.w);
    }
    #pragma unroll
    for (int off = 1; off < 64; off <<= 1) {
        m4.x = fmaxf(m4.x, __shfl_xor(m4.x, off));
        m4.y = fmaxf(m4.y, __shfl_xor(m4.y, off));
        m4.z = fmaxf(m4.z, __shfl_xor(m4.z, off));
        m4.w = fmaxf(m4.w, __shfl_xor(m4.w, off));
    }
    if (lane == 0) {
        red[wave][0] = m4.x; red[wave][1] = m4.y;
        red[wave][2] = m4.z; red[wave][3] = m4.w;
    }
    __syncthreads();
    float4 M;
    M.x = fmaxf(fmaxf(red[0][0], red[1][0]), fmaxf(red[2][0], red[3][0]));
    M.y = fmaxf(fmaxf(red[0][1], red[1][1]), fmaxf(red[2][1], red[3][1]));
    M.z = fmaxf(fmaxf(red[0][2], red[1][2]), fmaxf(red[2][2], red[3][2]));
    M.w = fmaxf(fmaxf(red[0][3], red[1][3]), fmaxf(red[2][3], red[3][3]));
    __syncthreads();

    float4 l4; l4.x = 0.f; l4.y = 0.f; l4.z = 0.f; l4.w = 0.f;
    for (int s = tid; s < 2049; s += 256) {
        float4 v = *(const float4*)&scb[(size_t)s * 32];
        v.x = __expf(v.x - M.x); v.y = __expf(v.y - M.y);
        v.z = __expf(v.z - M.z); v.w = __expf(v.w - M.w);
        *(float4*)&scb[(size_t)s * 32] = v;
        l4.x += v.x; l4.y += v.y; l4.z += v.z; l4.w += v.w;
    }
    #pragma unroll
    for (int off = 1; off < 64; off <<= 1) {
        l4.x += __shfl_xor(l4.x, off);
        l4.y += __shfl_xor(l4.y, off);
        l4.z += __shfl_xor(l4.z, off);
        l4.w += __shfl_xor(l4.w, off);
    }
    if (lane == 0) {
        red[wave][0] = l4.x; red[wave][1] = l4.y;
        red[wave][2] = l4.z; red[wave][3] = l4.w;
    }
    __syncthreads();
    if (tid < 4) {
        float L = red[0][tid] + red[1][tid] + red[2][tid] + red[3][tid];
        linv[(size_t)g * 4 + tid] = 1.0f / L;
    }
}

// ---------------------------------------------------------------------------
// PV, full-row streaming, same lane mapping as attn_scores. Each lane
// accumulates o[4 heads][8 floats] for its (kv, d-slice); p row is a 16B
// broadcast per 16-lane group. Cross-team reduce via pad-33 LDS (conflict-
// free scalar ops). Emits normalized partial [32 kvh][128] to PA[blk].
// Chunk 63 team 1 adds the new token.
// ---------------------------------------------------------------------------
__global__ __launch_bounds__(256) void attn_pv(
    const float* __restrict__ qkv, const float* __restrict__ cv,
    const float* __restrict__ sc, const float* __restrict__ linv,
    float* __restrict__ pa)
{
    __shared__ float sbuf[128 * 33];
    const int blk = blockIdx.x;
    const int c = blk & 63;
    const int b = blk >> 6;
    const int t = threadIdx.x;
    const int jj = t & 15;
    const int kv = (t >> 4) & 7;
    const int tm = t >> 7;

    float4 acc[4][2];
    #pragma unroll
    for (int h = 0; h < 4; ++h) {
        #pragma unroll
        for (int u = 0; u < 2; ++u) { acc[h][u].x=0.f; acc[h][u].y=0.f; acc[h][u].z=0.f; acc[h][u].w=0.f; }
    }

    const int r0 = c * 32 + tm * 16;
    const float* vbase = cv + ((size_t)b * 2048 + r0) * 1024 + kv * 128 + jj * 8;
    const float* scb = sc + (size_t)b * 65664 + kv * 4;

    for (int r = 0; r < 16; r += 2) {
        float4 va[2][2];
        float4 p4[2];
        #pragma unroll
        for (int u = 0; u < 2; ++u) {
            va[u][0] = *(const float4*)(vbase + (size_t)(r + u) * 1024);
            va[u][1] = *(const float4*)(vbase + (size_t)(r + u) * 1024 + 4);
            p4[u] = *(const float4*)&scb[(size_t)(r0 + r + u) * 32];
        }
        #pragma unroll
        for (int u = 0; u < 2; ++u) {
            acc[0][0].x += p4[u].x*va[u][0].x; acc[0][0].y += p4[u].x*va[u][0].y;
            acc[0][0].z += p4[u].x*va[u][0].z; acc[0][0].w += p4[u].x*va[u][0].w;
            acc[0][1].x += p4[u].x*va[u][1].x; acc[0][1].y += p4[u].x*va[u][1].y;
            acc[0][1].z += p4[u].x*va[u][1].z; acc[0][1].w += p4[u].x*va[u][1].w;
            acc[1][0].x += p4[u].y*va[u][0].x; acc[1][0].y += p4[u].y*va[u][0].y;
            acc[1][0].z += p4[u].y*va[u][0].z; acc[1][0].w += p4[u].y*va[u][0].w;
            acc[1][1].x += p4[u].y*va[u][1].x; acc[1][1].y += p4[u].y*va[u][1].y;
            acc[1][1].z += p4[u].y*va[u][1].z; acc[1][1].w += p4[u].y*va[u][1].w;
            acc[2][0].x += p4[u].z*va[u][0].x; acc[2][0].y += p4[u].z*va[u][0].y;
            acc[2][0].z += p4[u].z*va[u][0].z; acc[2][0].w += p4[u].z*va[u][0].w;
            acc[2][1].x += p4[u].z*va[u][1].x; acc[2][1].y += p4[u].z*va[u][1].y;
            acc[2][1].z += p4[u].z*va[u][1].z; acc[2][1].w += p4[u].z*va[u][1].w;
            acc[3][0].x += p4[u].w*va[u][0].x; acc[3][0].y += p4[u].w*va[u][0].y;
            acc[3][0].z += p4[u].w*va[u][0].z; acc[3][0].w += p4[u].w*va[u][0].w;
            acc[3][1].x += p4[u].w*va[u][1].x; acc[3][1].y += p4[u].w*va[u][1].y;
            acc[3][1].z += p4[u].w*va[u][1].z; acc[3][1].w += p4[u].w*va[u][1].w;
        }
    }

    if (c == 63 && tm == 1) {
        const float* vr = qkv + (size_t)b * 6144 + 5120 + kv * 128 + jj * 8;
        float4 v0 = *(const float4*)vr;
        float4 v1 = *(const float4*)(vr + 4);
        float4 p = *(const float4*)&scb[(size_t)2048 * 32];
        acc[0][0].x += p.x*v0.x; acc[0][0].y += p.x*v0.y; acc[0][0].z += p.x*v0.z; acc[0][0].w += p.x*v0.w;
        acc[0][1].x += p.x*v1.x; acc[0][1].y += p.x*v1.y; acc[0][1].z += p.x*v1.z; acc[0][1].w += p.x*v1.w;
        acc[1][0].x += p.y*v0.x; acc[1][0].y += p.y*v0.y; acc[1][0].z += p.y*v0.z; acc[1][0].w += p.y*v0.w;
        acc[1][1].x += p.y*v1.x; acc[1][1].y += p.y*v1.y; acc[1][1].z += p.y*v1.z; acc[1][1].w += p.y*v1.w;
        acc[2][0].x += p.z*v0.x; acc[2][0].y += p.z*v0.y; acc[2][0].z += p.z*v0.z; acc[2][0].w += p.z*v0.w;
        acc[2][1].x += p.z*v1.x; acc[2][1].y += p.z*v1.y; acc[2][1].z += p.z*v1.z; acc[2][1].w += p.z*v1.w;
        acc[3][0].x += p.w*v0.x; acc[3][0].y += p.w*v0.y; acc[3][0].z += p.w*v0.z; acc[3][0].w += p.w*v0.w;
        acc[3][1].x += p.w*v1.x; acc[3][1].y += p.w*v1.y; acc[3][1].z += p.w*v1.z; acc[3][1].w += p.w*v1.w;
    }

    // normalize so combine is a plain sum
    {
        float4 li = *(const float4*)&linv[(size_t)((b * 8 + kv) * 4)];
        #pragma unroll
        for (int u = 0; u < 2; ++u) {
            acc[0][u].x *= li.x; acc[0][u].y *= li.x; acc[0][u].z *= li.x; acc[0][u].w *= li.x;
            acc[1][u].x *= li.y; acc[1][u].y *= li.y; acc[1][u].z *= li.y; acc[1][u].w *= li.y;
            acc[2][u].x *= li.z; acc[2][u].y *= li.z; acc[2][u].z *= li.z; acc[2][u].w *= li.z;
            acc[3][u].x *= li.w; acc[3][u].y *= li.w; acc[3][u].z *= li.w; acc[3][u].w *= li.w;
        }
    }

    // cross-team reduce: team 1 -> LDS (pad 33, conflict-free), team 0 adds
    if (tm == 1) {
        const int li_ = t - 128;
        float* d = &sbuf[li_ * 33];
        #pragma unroll
        for (int h = 0; h < 4; ++h) {
            d[h*8+0] = acc[h][0].x; d[h*8+1] = acc[h][0].y;
            d[h*8+2] = acc[h][0].z; d[h*8+3] = acc[h][0].w;
            d[h*8+4] = acc[h][1].x; d[h*8+5] = acc[h][1].y;
            d[h*8+6] = acc[h][1].z; d[h*8+7] = acc[h][1].w;
        }
    }
    __syncthreads();
    if (tm == 0) {
        const float* s_ = &sbuf[t * 33];
        #pragma unroll
        for (int h = 0; h < 4; ++h) {
            acc[h][0].x += s_[h*8+0]; acc[h][0].y += s_[h*8+1];
            acc[h][0].z += s_[h*8+2]; acc[h][0].w += s_[h*8+3];
            acc[h][1].x += s_[h*8+4]; acc[h][1].y += s_[h*8+5];
            acc[h][1].z += s_[h*8+6]; acc[h][1].w += s_[h*8+7];
        }
        float* rec = pa + (size_t)blk * 4096 + (kv * 4) * 128 + jj * 8;
        #pragma unroll
        for (int h = 0; h < 4; ++h) {
            *(float4*)(rec + h * 128)     = acc[h][0];
            *(float4*)(rec + h * 128 + 4) = acc[h][1];
        }
    }
}

// ---------------------------------------------------------------------------
// Combine 64 normalized PV partials per b: plain sum. grid 512 x 256.
// ---------------------------------------------------------------------------
__global__ __launch_bounds__(256) void attn_combine(
    const float* __restrict__ pa, float* __restrict__ ao)
{
    const int blk = blockIdx.x;
    const int b = blk >> 4, seg = blk & 15;
    const int j = seg * 256 + threadIdx.x;
    const float* base = pa + (size_t)b * 64 * 4096 + j;
    float v = 0.f;
    #pragma unroll 8
    for (int c2 = 0; c2 < 64; ++c2) v += base[(size_t)c2 * 4096];
    ao[(size_t)b * 4096 + j] = v;
}

// ---------------------------------------------------------------------------
// Reduce 32 split-K partials for output projection -> d_out
// ---------------------------------------------------------------------------
__global__ __launch_bounds__(128) void reduce_out(
    const float* __restrict__ P, float* __restrict__ out)
{
    int t = blockIdx.x * 128 + threadIdx.x;   // float2 units
    int b = t >> 11;
    int cp = t & 2047;
    int n = cp * 2;
    float sx = 0.f, sy = 0.f;
    #pragma unroll
    for (int ks = 0; ks < 32; ++ks) {
        float2 v = *(const float2*)&P[((size_t)ks * 32 + b) * 4096 + n];
        sx += v.x; sy += v.y;
    }
    float2 o; o.x = sx; o.y = sy;
    *(float2*)&out[(size_t)b * 4096 + n] = o;
}

extern "C" void kernel_launch(void* const* d_in, const int* in_sizes, int n_in,
                              void* d_out, int out_size, void* d_ws, size_t ws_size,
                              hipStream_t stream) {
    const float* x  = (const float*)d_in[0];
    const float* wq = (const float*)d_in[1];
    const float* wk = (const float*)d_in[2];
    const float* wv = (const float*)d_in[3];
    const float* wo = (const float*)d_in[4];
    const float* ck = (const float*)d_in[5];
    const float* cv = (const float*)d_in[6];
    const float* fr = (const float*)d_in[7];
    float* out = (float*)d_out;
    float* ws  = (float*)d_ws;

    float* P1   = ws + WS_P1;
    float* qkv  = ws + WS_QKV;
    float* attn = ws + WS_ATTN;
    float* P2   = ws + WS_P2;
    float* SC   = ws + WS_SC;
    float* LINV = ws + WS_LINV;
    float* PA   = ws + WS_PA;

    dim3 g1(24, 32);
    gemm_skinny<<<g1, 256, 0, stream>>>(x, wq, 4096, 4096, wk, 5120, 1024,
                                        wv, 1024, P1, 6144);
    reduce_rope<<<768, 128, 0, stream>>>(P1, fr, qkv);
    attn_scores<<<2048, 256, 0, stream>>>(qkv, ck, SC);
    attn_softmax<<<256, 256, 0, stream>>>(SC, LINV);
    attn_pv<<<2048, 256, 0, stream>>>(qkv, cv, SC, LINV, PA);
    attn_combine<<<512, 256, 0, stream>>>(PA, attn);
    dim3 g4(16, 32);
    gemm_skinny<<<g4, 256, 0, stream>>>(attn, wo, 4096, 4096, wo, 4096, 4096,
                                        wo, 4096, P2, 4096);
    reduce_out<<<512, 128, 0, stream>>>(P2, out);
}

// Round 11
// 184.086 us; speedup vs baseline: 1.3434x; 1.3434x over previous
//
#include <hip/hip_runtime.h>

// Shapes: B=32, S_NEW=1, DIM=4096, H=32, KV=8, HD=128, PREV=2048, SEQ=2049
// All inputs/outputs fp32.
//
// ws layout (float offsets):
//   P1   [32][32][6144] @ 0        (6291456) qkv split-K partials
//   qkv  [32][6144]     @ 6291456  (196608)  rope'd q (scaled), k_new, v_new
//   attn [32][4096]     @ 6488064  (131072)  attention output (b, h, d)
//   P2   [32][32][4096] @ 6619136  (4194304) out-proj split-K partials
//   PA   [1024][520]    @ 10813440 (532480)  flash partials: m[4],l[4],o[4][128]

#define WS_P1   0
#define WS_QKV  6291456
#define WS_ATTN 6488064
#define WS_P2   6619136
#define WS_PA   10813440

// ---------------------------------------------------------------------------
// Skinny GEMM partial: P[ks][b][n] = sum_{k in 128-chunk} X[b][k] * W[k][n]
// grid: (Ntot/256, 32), block: 256 threads = 128 colpairs x 2 k-groups.
// ---------------------------------------------------------------------------
__global__ __launch_bounds__(256) void gemm_skinny(
    const float* __restrict__ X,
    const float* __restrict__ W0, int e0, int ld0,
    const float* __restrict__ W1, int e1, int ld1,
    const float* __restrict__ W2, int ld2,
    float* __restrict__ P, int Ntot)
{
    __shared__ float x_t[128][36];     // transposed x chunk [kk][b], pad 36
    __shared__ float2 red[128][33];    // 2-way kg reduce, pad 33

    const int nb = blockIdx.x * 256;
    const float* W; int ld, noff;
    if (nb < e0)      { W = W0; ld = ld0; noff = 0;  }
    else if (nb < e1) { W = W1; ld = ld1; noff = e0; }
    else              { W = W2; ld = ld2; noff = e1; }

    const int k0  = blockIdx.y * 128;
    const int tid = threadIdx.x;
    const int cp  = tid & 127;
    const int kg  = tid >> 7;
    const int nn  = nb - noff + cp * 2;

    #pragma unroll
    for (int i = 0; i < 16; ++i) {
        int idx = tid + i * 256;
        int bb = idx >> 7, kk = idx & 127;
        x_t[kk][bb] = X[(size_t)bb * 4096 + k0 + kk];
    }
    __syncthreads();

    float2 acc[32];
    #pragma unroll
    for (int b = 0; b < 32; ++b) { acc[b].x = 0.f; acc[b].y = 0.f; }

    const float* Wp = W + (size_t)k0 * ld + nn;
    for (int kk0 = kg * 64; kk0 < kg * 64 + 64; kk0 += 8) {
        float2 w[8];
        #pragma unroll
        for (int u = 0; u < 8; ++u)
            w[u] = *(const float2*)&Wp[(size_t)(kk0 + u) * ld];
        #pragma unroll
        for (int u = 0; u < 8; ++u) {
            const float* xr = x_t[kk0 + u];
            #pragma unroll
            for (int bq = 0; bq < 8; ++bq) {
                float4 xv = *(const float4*)&xr[bq * 4];
                acc[bq*4+0].x += xv.x * w[u].x; acc[bq*4+0].y += xv.x * w[u].y;
                acc[bq*4+1].x += xv.y * w[u].x; acc[bq*4+1].y += xv.y * w[u].y;
                acc[bq*4+2].x += xv.z * w[u].x; acc[bq*4+2].y += xv.z * w[u].y;
                acc[bq*4+3].x += xv.w * w[u].x; acc[bq*4+3].y += xv.w * w[u].y;
            }
        }
    }

    if (kg == 1) {
        #pragma unroll
        for (int b = 0; b < 32; ++b) red[cp][b] = acc[b];
    }
    __syncthreads();
    if (kg == 0) {
        const int ks = blockIdx.y;
        #pragma unroll
        for (int b = 0; b < 32; ++b) {
            float2 o = red[cp][b];
            float2 v; v.x = acc[b].x + o.x; v.y = acc[b].y + o.y;
            *(float2*)&P[((size_t)ks * 32 + b) * Ntot + nb + cp * 2] = v;
        }
    }
}

// ---------------------------------------------------------------------------
// Reduce 32 split-K partials for QKV + fused RoPE (+ 1/sqrt(128) on q).
// ---------------------------------------------------------------------------
__global__ __launch_bounds__(256) void reduce_rope(
    const float* __restrict__ P, const float* __restrict__ freqs,
    float* __restrict__ qkv)
{
    int t = blockIdx.x * 256 + threadIdx.x;
    int b = t / 3072;
    int cp = t - b * 3072;
    int n = cp * 2;
    float sx = 0.f, sy = 0.f;
    #pragma unroll
    for (int ks = 0; ks < 32; ++ks) {
        float2 v = *(const float2*)&P[((size_t)ks * 32 + b) * 6144 + n];
        sx += v.x; sy += v.y;
    }
    if (n < 5120) {
        int d = n & 127;
        float fr = freqs[d >> 1];
        float c = cosf(fr), s = sinf(fr);
        float ra = sx * c - sy * s;
        float rb = sx * s + sy * c;
        if (n < 4096) {
            const float sc = 0.08838834764831845f;  // 1/sqrt(128)
            ra *= sc; rb *= sc;
        }
        sx = ra; sy = rb;
    }
    float2 o; o.x = sx; o.y = sy;
    *(float2*)&qkv[(size_t)b * 6144 + n] = o;
}

// ---------------------------------------------------------------------------
// Flash-decode split-S attention. grid 1024 = (b, kv, chunk c of 512 rows),
// block 256 (4 waves). Emits per-chunk m[4], l[4], unnormalized o[4][128].
// Chunk 3 additionally handles the new token (row 2048).
// ---------------------------------------------------------------------------
__global__ __launch_bounds__(256, 4) void attn_split(
    const float* __restrict__ qkv,
    const float* __restrict__ ck, const float* __restrict__ cv,
    float* __restrict__ pa)
{
    __shared__ float sbuf[4096];   // sc[4][520] (2080) then op[8][512] (4096)
    __shared__ float pm[4], pl[4];

    const int blk = blockIdx.x;
    const int c   = blk & 3;
    const int kv  = (blk >> 2) & 7;
    const int b   = blk >> 5;
    const int tid = threadIdx.x;
    const int wave = tid >> 6, lane = tid & 63;
    const int psub = (lane >> 4) & 3, dl = lane & 15;
    const int s0 = c * 512;

    // q fragments: 4 heads x this lane's 8-dim slice (pre-scaled)
    float q[4][8];
    {
        const float* qb = qkv + (size_t)b * 6144 + kv * 512 + dl * 8;
        #pragma unroll
        for (int h = 0; h < 4; ++h) {
            float4 a = *(const float4*)&qb[h * 128];
            float4 e = *(const float4*)&qb[h * 128 + 4];
            q[h][0]=a.x; q[h][1]=a.y; q[h][2]=a.z; q[h][3]=a.w;
            q[h][4]=e.x; q[h][5]=e.y; q[h][6]=e.z; q[h][7]=e.w;
        }
    }

    // new-token score (chunk 3 only), lanes 0..15
    if (c == 3 && tid < 16) {
        const float* kr = qkv + (size_t)b * 6144 + 4096 + kv * 128 + dl * 8;
        float4 k0 = *(const float4*)kr;
        float4 k1 = *(const float4*)(kr + 4);
        float p[4];
        #pragma unroll
        for (int h = 0; h < 4; ++h) {
            p[h] = q[h][0]*k0.x + q[h][1]*k0.y + q[h][2]*k0.z + q[h][3]*k0.w
                 + q[h][4]*k1.x + q[h][5]*k1.y + q[h][6]*k1.z + q[h][7]*k1.w;
        }
        #pragma unroll
        for (int off = 1; off < 16; off <<= 1) {
            #pragma unroll
            for (int h = 0; h < 4; ++h) p[h] += __shfl_xor(p[h], off);
        }
        if (dl == 0) {
            #pragma unroll
            for (int h = 0; h < 4; ++h) sbuf[h * 520 + 512] = p[h];
        }
    }

    // phase 1: scores for this chunk's 512 rows, 4-deep load batching
    const float* kbase = ck + ((size_t)b * 2048 * 8 + kv) * 128
                            + (size_t)s0 * 1024;
    const int srow = wave * 4 + psub;       // 0..15
    for (int it0 = 0; it0 < 32; it0 += 4) {
        float4 kA[4][2];
        #pragma unroll
        for (int u = 0; u < 4; ++u) {
            const float* kr = kbase + (size_t)((it0 + u) * 16 + srow) * 1024 + dl * 8;
            kA[u][0] = *(const float4*)kr;
            kA[u][1] = *(const float4*)(kr + 4);
        }
        #pragma unroll
        for (int u = 0; u < 4; ++u) {
            int s = (it0 + u) * 16 + srow;
            float p[4];
            #pragma unroll
            for (int h = 0; h < 4; ++h) {
                p[h] = q[h][0]*kA[u][0].x + q[h][1]*kA[u][0].y
                     + q[h][2]*kA[u][0].z + q[h][3]*kA[u][0].w
                     + q[h][4]*kA[u][1].x + q[h][5]*kA[u][1].y
                     + q[h][6]*kA[u][1].z + q[h][7]*kA[u][1].w;
            }
            #pragma unroll
            for (int off = 1; off < 16; off <<= 1) {
                #pragma unroll
                for (int h = 0; h < 4; ++h) p[h] += __shfl_xor(p[h], off);
            }
            if (dl == 0) {
                #pragma unroll
                for (int h = 0; h < 4; ++h) sbuf[h * 520 + s] = p[h];
            }
        }
    }
    __syncthreads();

    // partial softmax: wave w owns head w (64 lanes over 512/513 entries)
    {
        const int h = wave;
        const int nrow = (c == 3) ? 513 : 512;
        float m = -1e30f;
        for (int s = lane; s < nrow; s += 64) m = fmaxf(m, sbuf[h * 520 + s]);
        #pragma unroll
        for (int off = 1; off < 64; off <<= 1) m = fmaxf(m, __shfl_xor(m, off));
        float sum = 0.f;
        for (int s = lane; s < nrow; s += 64) {
            float p = __expf(sbuf[h * 520 + s] - m);
            sbuf[h * 520 + s] = p;
            sum += p;
        }
        #pragma unroll
        for (int off = 1; off < 64; off <<= 1) sum += __shfl_xor(sum, off);
        if (lane == 0) { pm[h] = m; pl[h] = sum; }
    }
    __syncthreads();

    // phase 2: o_partial = P @ V over this chunk, 4-deep batching
    const int grp = tid >> 5, l32 = tid & 31, d4 = l32 * 4;
    float4 acc[4];
    #pragma unroll
    for (int hh = 0; hh < 4; ++hh) { acc[hh].x=0.f; acc[hh].y=0.f; acc[hh].z=0.f; acc[hh].w=0.f; }
    const float* vbase = cv + ((size_t)b * 2048 * 8 + kv) * 128
                            + (size_t)s0 * 1024;
    for (int it = 0; it < 16; ++it) {
        float4 vv[4];
        float pp[4][4];
        #pragma unroll
        for (int j = 0; j < 4; ++j) {
            int s = it * 32 + j * 8 + grp;
            vv[j] = *(const float4*)&vbase[(size_t)s * 1024 + d4];
        }
        #pragma unroll
        for (int j = 0; j < 4; ++j) {
            int s = it * 32 + j * 8 + grp;
            #pragma unroll
            for (int hh = 0; hh < 4; ++hh) pp[j][hh] = sbuf[hh * 520 + s];
        }
        #pragma unroll
        for (int j = 0; j < 4; ++j) {
            #pragma unroll
            for (int hh = 0; hh < 4; ++hh) {
                acc[hh].x += pp[j][hh] * vv[j].x;
                acc[hh].y += pp[j][hh] * vv[j].y;
                acc[hh].z += pp[j][hh] * vv[j].z;
                acc[hh].w += pp[j][hh] * vv[j].w;
            }
        }
    }
    if (c == 3 && grp == 0) {
        const float* vr = qkv + (size_t)b * 6144 + 5120 + kv * 128;
        float4 v = *(const float4*)&vr[d4];
        #pragma unroll
        for (int hh = 0; hh < 4; ++hh) {
            float p = sbuf[hh * 520 + 512];
            acc[hh].x += p * v.x; acc[hh].y += p * v.y;
            acc[hh].z += p * v.z; acc[hh].w += p * v.w;
        }
    }
    __syncthreads();   // sc reads done; sbuf becomes op[8][512]

    #pragma unroll
    for (int hh = 0; hh < 4; ++hh)
        *(float4*)&sbuf[grp * 512 + hh * 128 + d4] = acc[hh];
    __syncthreads();

    float* rec = pa + (size_t)blk * 520;
    for (int t = tid; t < 512; t += 256) {
        int hh = t >> 7, d = t & 127;
        float v = 0.f;
        #pragma unroll
        for (int g = 0; g < 8; ++g) v += sbuf[g * 512 + hh * 128 + d];
        rec[8 + hh * 128 + d] = v;
    }
    if (tid < 4) { rec[tid] = pm[tid]; rec[4 + tid] = pl[tid]; }
}

// ---------------------------------------------------------------------------
// Combine 4 flash partials per (b,kv): rescale by exp(m_c - M), normalize.
// grid 256 = (b*8+kv), block 128 (= d).
// ---------------------------------------------------------------------------
__global__ __launch_bounds__(128) void attn_combine(
    const float* __restrict__ pa, float* __restrict__ ao)
{
    __shared__ float w_[4][4];   // [c][h] = exp(m_c - M) / L
    const int g = blockIdx.x;
    const int d = threadIdx.x;
    const float* rec = pa + (size_t)g * 4 * 520;

    if (d < 4) {
        float m0 = rec[0*520 + d], m1 = rec[1*520 + d];
        float m2 = rec[2*520 + d], m3 = rec[3*520 + d];
        float M = fmaxf(fmaxf(m0, m1), fmaxf(m2, m3));
        float e0 = __expf(m0 - M), e1 = __expf(m1 - M);
        float e2 = __expf(m2 - M), e3 = __expf(m3 - M);
        float L = rec[0*520 + 4 + d] * e0 + rec[1*520 + 4 + d] * e1
                + rec[2*520 + 4 + d] * e2 + rec[3*520 + 4 + d] * e3;
        float inv = 1.0f / L;
        w_[0][d] = e0 * inv; w_[1][d] = e1 * inv;
        w_[2][d] = e2 * inv; w_[3][d] = e3 * inv;
    }
    __syncthreads();

    #pragma unroll
    for (int h = 0; h < 4; ++h) {
        float v = 0.f;
        #pragma unroll
        for (int c = 0; c < 4; ++c)
            v += rec[c*520 + 8 + h*128 + d] * w_[c][h];
        ao[(size_t)g * 512 + h * 128 + d] = v;
    }
}

// ---------------------------------------------------------------------------
// Reduce 32 split-K partials for output projection -> d_out
// ---------------------------------------------------------------------------
__global__ __launch_bounds__(256) void reduce_out(
    const float* __restrict__ P, float* __restrict__ out)
{
    int t = blockIdx.x * 256 + threadIdx.x;
    int b = t >> 11;
    int cp = t & 2047;
    int n = cp * 2;
    float sx = 0.f, sy = 0.f;
    #pragma unroll
    for (int ks = 0; ks < 32; ++ks) {
        float2 v = *(const float2*)&P[((size_t)ks * 32 + b) * 4096 + n];
        sx += v.x; sy += v.y;
    }
    float2 o; o.x = sx; o.y = sy;
    *(float2*)&out[(size_t)b * 4096 + n] = o;
}

extern "C" void kernel_launch(void* const* d_in, const int* in_sizes, int n_in,
                              void* d_out, int out_size, void* d_ws, size_t ws_size,
                              hipStream_t stream) {
    const float* x  = (const float*)d_in[0];
    const float* wq = (const float*)d_in[1];
    const float* wk = (const float*)d_in[2];
    const float* wv = (const float*)d_in[3];
    const float* wo = (const float*)d_in[4];
    const float* ck = (const float*)d_in[5];
    const float* cv = (const float*)d_in[6];
    const float* fr = (const float*)d_in[7];
    float* out = (float*)d_out;
    float* ws  = (float*)d_ws;

    float* P1   = ws + WS_P1;
    float* qkv  = ws + WS_QKV;
    float* attn = ws + WS_ATTN;
    float* P2   = ws + WS_P2;
    float* PA   = ws + WS_PA;

    dim3 g1(24, 32);
    gemm_skinny<<<g1, 256, 0, stream>>>(x, wq, 4096, 4096, wk, 5120, 1024,
                                        wv, 1024, P1, 6144);
    reduce_rope<<<384, 256, 0, stream>>>(P1, fr, qkv);
    attn_split<<<1024, 256, 0, stream>>>(qkv, ck, cv, PA);
    attn_combine<<<256, 128, 0, stream>>>(PA, attn);
    dim3 g4(16, 32);
    gemm_skinny<<<g4, 256, 0, stream>>>(attn, wo, 4096, 4096, wo, 4096, 4096,
                                        wo, 4096, P2, 4096);
    reduce_out<<<256, 256, 0, stream>>>(P2, out);
}